// Round 15
// baseline (1049.636 us; speedup 1.0000x reference)
//
#include <hip/hip_runtime.h>
#include <hip/hip_bf16.h>
#include <stdint.h>

// ---------------------------------------------------------------------------
// DEER forward, MI355X. L=12, B=2, T=512, C=768, F=3072, M=B*T=1024.
// bf16 MFMA GEMMs (fp32 accum), analytic JVP, threefry2x32 Rademacher v.
// R15: R14 (measured-best) + safe fusions, numerics unchanged:
//      (a) it0 scan + it1 ln_iter fused (scan_ln): states[l+1] update stays
//          in registers and feeds layer-(l+1)'s LN; -1 launch, -38MB traffic.
//      (b) final scan "lite": states[1..11] dead after it1 -> recurrence from
//          resA only + states[12] read + d_out write (153MB -> 81MB).
//      GEMM core/pipeline byte-identical to R14 (R7 structure).
// ---------------------------------------------------------------------------

typedef __bf16 bf16;
typedef __bf16 bf16x8 __attribute__((ext_vector_type(8)));
typedef float f32x4 __attribute__((ext_vector_type(4)));

#define LAY_A   1572864   // 2048*768
#define LAY_W   2359296   // 3072*768
#define LAY_Z   6291456   // 2048*3072
#define LAY_S   786432    // 1024*768

#define GLDS16(gp, lp) __builtin_amdgcn_global_load_lds(                      \
    (const __attribute__((address_space(1))) void*)(gp),                      \
    (__attribute__((address_space(3))) void*)(lp), 16, 0, 0)

#define WAITVM(N) asm volatile("s_waitcnt vmcnt(%0)" :: "n"(N) : "memory")
#define CFENCE()  asm volatile("" ::: "memory")

// ------------------------- threefry2x32 (host+device) ----------------------
#define TF_ROT(x0, x1, n) { x0 += x1; x1 = (x1 << n) | (x1 >> (32 - n)); x1 ^= x0; }
__host__ __device__ __forceinline__ void threefry2x32(
    uint32_t k1, uint32_t k2, uint32_t c0, uint32_t c1, uint32_t& o0, uint32_t& o1)
{
  const uint32_t ks2 = k1 ^ k2 ^ 0x1BD11BDAu;
  uint32_t x0 = c0 + k1, x1 = c1 + k2;
  TF_ROT(x0,x1,13) TF_ROT(x0,x1,15) TF_ROT(x0,x1,26) TF_ROT(x0,x1,6)
  x0 += k2;  x1 += ks2 + 1u;
  TF_ROT(x0,x1,17) TF_ROT(x0,x1,29) TF_ROT(x0,x1,16) TF_ROT(x0,x1,24)
  x0 += ks2; x1 += k1 + 2u;
  TF_ROT(x0,x1,13) TF_ROT(x0,x1,15) TF_ROT(x0,x1,26) TF_ROT(x0,x1,6)
  x0 += k1;  x1 += k2 + 3u;
  TF_ROT(x0,x1,17) TF_ROT(x0,x1,29) TF_ROT(x0,x1,16) TF_ROT(x0,x1,24)
  x0 += k2;  x1 += ks2 + 4u;
  TF_ROT(x0,x1,13) TF_ROT(x0,x1,15) TF_ROT(x0,x1,26) TF_ROT(x0,x1,6)
  x0 += ks2; x1 += k1 + 5u;
  o0 = x0; o1 = x1;
}

// --------------------- weight transpose fp32 -> bf16^T ---------------------
__global__ __launch_bounds__(256) void transpose_kernel(
    const float* __restrict__ w, bf16* __restrict__ wt, int R, int Cc)
{
  __shared__ float tile[32][33];
  const int l = blockIdx.z;
  const float* wp = w + (size_t)l * R * Cc;
  bf16* wtp = wt + (size_t)l * R * Cc;
  const int c0 = blockIdx.x * 32;
  const int r0 = blockIdx.y * 32;
  const int tx = threadIdx.x & 31, ty = threadIdx.x >> 5;
  #pragma unroll
  for (int q = 0; q < 4; ++q)
    tile[ty + q * 8][tx] = wp[(size_t)(r0 + ty + q * 8) * Cc + c0 + tx];
  __syncthreads();
  // packed bf16x2 stores: thread -> 2 output rows x 2 consecutive cols
  const int orow = threadIdx.x >> 4;        // 0..15
  const int oc   = (threadIdx.x & 15) * 2;  // even col
  #pragma unroll
  for (int q = 0; q < 2; ++q) {
    const int r = orow + q * 16;
    const unsigned short lo = __builtin_bit_cast(unsigned short,
                                                 (bf16)tile[oc][r]);
    const unsigned short hi = __builtin_bit_cast(unsigned short,
                                                 (bf16)tile[oc + 1][r]);
    *(unsigned int*)&wtp[(size_t)(c0 + r) * R + r0 + oc] =
        (unsigned int)lo | ((unsigned int)hi << 16);
  }
}

// ------------------------------ gelu helper --------------------------------
// tanh via native exp: t = 1 - 2/(e^{2u}+1). Limits correct at +/-inf.
__device__ __forceinline__ void gelu2(float z, float& h, float& dg)
{
  const float z2 = z * z;
  const float u = 0.7978845608028654f * (z + 0.044715f * z2 * z);
  const float e = __expf(2.0f * u);
  const float t = 1.0f - 2.0f / (e + 1.0f);
  h = 0.5f * z * (1.f + t);
  dg = 0.5f * (1.f + t) +
       0.5f * z * (1.f - t * t) * 0.7978845608028654f * (1.f + 0.134145f * z2);
}

// ------------------------------ GEMM core ----------------------------------
// True R7 kernel. 128x128 tile, BK=64, 256 threads = 4 waves (2M x 2N),
// per-wave 64x64 out. Depth-1 counted-vmcnt pipeline over 2 LDS buffers
// (64 KiB -> 2 blocks/CU for cross-block phase overlap).
// MODE 0: gemm1 warm  (M=1024): zh = gelu(acc + b1), all rows.
// MODE 1: gemm1 iter  (M=2048 interleaved): even h=gelu(z), odd dh=dg*dz.
// MODE 2: gemm2 warm : states[l+1] = acc + b2 + x0.
// MODE 3: gemm2 iter  (interleaved): even res, odd A = 1 + acc*v.
template <int MODE>
__global__ __launch_bounds__(256, 2) void gemm_dbuf(
    const bf16* __restrict__ Abase, const bf16* __restrict__ Bbase,
    bf16* __restrict__ zh_out, float* __restrict__ states,
    float* __restrict__ resA, const bf16* __restrict__ vbuf,
    const float* __restrict__ bias1, const float* __restrict__ b2,
    const float* __restrict__ x0, int Mt)
{
  constexpr int LDAB  = (MODE <= 1) ? 768 : 3072;
  constexpr int NKT   = (MODE <= 1) ? 12 : 48;      // K/64
  constexpr int NTN   = (MODE <= 1) ? 24 : 6;       // N/128
  constexpr int ACH   = 16;                 // A chunks (128 rows / 8)
  constexpr int BCH   = 16;                 // B chunks (128 rows / 8)
  constexpr int NCH   = (ACH + BCH) / 4;    // 8 loads per thread per tile
  constexpr int ABYTES = 16384;
  constexpr int TILE  = ABYTES + BCH * 1024;   // 32 KiB
  constexpr size_t LSA = (MODE <= 1) ? LAY_A : LAY_Z;

  __shared__ __align__(16) char lds[2][TILE];  // 64 KiB double buffer

  const int tid  = threadIdx.x;
  const int lane = tid & 63;
  const int wid  = tid >> 6;           // 0..3
  const int wr   = wid >> 1;           // 0..1  (M half)
  const int wc   = wid & 1;            // 0..1  (N half)
  const int r16  = lane & 15;
  const int hi   = lane >> 4;          // 0..3

  // T1: XCD-aware bijective swizzle (grids are multiples of 8)
  const int nwg = gridDim.x;
  const int bid = blockIdx.x;
  const int swz = (bid & 7) * (nwg >> 3) + (bid >> 3);
  const int per_l = Mt * NTN;
  const int l   = swz / per_l;
  const int rr_ = swz - l * per_l;
  const int mt  = rr_ / NTN;
  const int nt  = rr_ - mt * NTN;
  const int m0  = mt * 128, n0 = nt * 128;

  const bf16* A = Abase + (size_t)l * LSA   + (size_t)m0 * LDAB;
  const bf16* B = Bbase + (size_t)l * LAY_W + (size_t)n0 * LDAB;

  const int rsub = lane >> 3;               // 0..7 row within chunk
  const int c8   = (lane & 7) ^ rsub;       // swizzled 16B slot (involution)
  auto STAGE = [&](char* dst, int kt) {
    #pragma unroll
    for (int j = 0; j < NCH; ++j) {
      const int chunk = j * 4 + wid;
      if (chunk < ACH) {
        const int row = chunk * 8 + rsub;
        GLDS16(A + (size_t)row * LDAB + kt + c8 * 8, dst + chunk * 1024);
      } else {
        const int row = (chunk - ACH) * 8 + rsub;
        GLDS16(B + (size_t)row * LDAB + kt + c8 * 8,
               dst + ABYTES + (chunk - ACH) * 1024);
      }
    }
  };

  f32x4 acc[4][4] = {};

  auto COMPUTE = [&](const char* buf) {
    const char* As = buf;
    const char* Bs = buf + ABYTES;
    const int xw = (r16 & 7) << 4;        // read-side XOR (matches staging)
    #pragma unroll
    for (int kk = 0; kk < 2; ++kk) {
      const int cb = kk * 64;
      bf16x8 bfrag[4];
      #pragma unroll
      for (int ni = 0; ni < 4; ++ni) {
        const int rn = wc * 64 + ni * 16 + r16;
        bfrag[ni] = *(const bf16x8*)(Bs + rn * 128 + ((cb + hi * 16) ^ xw));
      }
      bf16x8 afrag[4];
      #pragma unroll
      for (int q = 0; q < 4; ++q) {
        const int rm = wr * 64 + q * 16 + r16;
        afrag[q] = *(const bf16x8*)(As + rm * 128 + ((cb + hi * 16) ^ xw));
      }
      #pragma unroll
      for (int q = 0; q < 4; ++q)
        #pragma unroll
        for (int ni = 0; ni < 4; ++ni)
          acc[q][ni] = __builtin_amdgcn_mfma_f32_16x16x32_bf16(
              afrag[q], bfrag[ni], acc[q][ni], 0, 0, 0);
    }
  };

  // ---- depth-1 counted-vmcnt pipeline (R5-proven) ----
  STAGE(lds[0], 0);
  STAGE(lds[1], 64);
  WAITVM(NCH);                         // tile 0 landed; tile 1 in flight
  __builtin_amdgcn_s_barrier();
  CFENCE();
  COMPUTE(lds[0]);
  #pragma unroll 1
  for (int t = 1; t < NKT; ++t) {
    CFENCE();
    __builtin_amdgcn_s_barrier();      // all waves done reading buf[(t+1)&1]
    CFENCE();
    if (t + 1 < NKT) {
      STAGE(lds[(t + 1) & 1], (t + 1) * 64);
      WAITVM(NCH);                     // tile t landed; t+1 stays in flight
    } else {
      WAITVM(0);                       // last tile: drain
    }
    __builtin_amdgcn_s_barrier();      // cross-wave: tile t visible to all
    CFENCE();
    COMPUTE(lds[t & 1]);
  }

  // ------------------------------ epilogue ---------------------------------
  #pragma unroll
  for (int mi = 0; mi < 4; ++mi) {
    const int row0 = m0 + wr * 64 + mi * 16 + hi * 4;
    #pragma unroll
    for (int ni = 0; ni < 4; ++ni) {
      const int col = n0 + wc * 64 + ni * 16 + r16;
      if (MODE == 0) {                  // warm gemm1: h = gelu(z), all rows
        bf16* Cp = zh_out + (size_t)l * LAY_Z;
        const float bias = bias1[l * 3072 + col];
        #pragma unroll
        for (int r = 0; r < 4; ++r) {
          float h, dg;
          gelu2(acc[mi][ni][r] + bias, h, dg);
          Cp[(size_t)(row0 + r) * 3072 + col] = (bf16)h;
        }
      } else if (MODE == 1) {           // iter gemm1: row pairs (z, dz)
        bf16* Cp = zh_out + (size_t)l * LAY_Z;
        const float bias = bias1[l * 3072 + col];
        #pragma unroll
        for (int p = 0; p < 2; ++p) {
          float h, dg;
          gelu2(acc[mi][ni][2 * p] + bias, h, dg);
          Cp[(size_t)(row0 + 2 * p) * 3072 + col] = (bf16)h;
          Cp[(size_t)(row0 + 2 * p + 1) * 3072 + col] =
              (bf16)(dg * acc[mi][ni][2 * p + 1]);
        }
      } else if (MODE == 2) {           // warm gemm2
        float* Sp = states + (size_t)(l + 1) * LAY_S;
        const float bb = b2[l * 768 + col];
        #pragma unroll
        for (int r = 0; r < 4; ++r)
          Sp[(size_t)(row0 + r) * 768 + col] =
              acc[mi][ni][r] + bb + x0[(size_t)(row0 + r) * 768 + col];
      } else {                          // iter gemm2: row pairs (res, Adiag)
        float* Rp = resA + (size_t)l * LAY_A;
        const float bb = b2[l * 768 + col];
        #pragma unroll
        for (int p = 0; p < 2; ++p) {
          const int tok = (row0 >> 1) + p;          // rows row0+2p, +2p+1
          Rp[(size_t)tok * 768 + col] = acc[mi][ni][2 * p] + bb
              + states[(size_t)l * LAY_S + (size_t)tok * 768 + col]
              - states[(size_t)(l + 1) * LAY_S + (size_t)tok * 768 + col];
          const float vv = (float)vbuf[(size_t)l * LAY_S +
                                       (size_t)tok * 768 + col];
          Rp[LAY_S + (size_t)tok * 768 + col] =
              1.0f + acc[mi][ni][2 * p + 1] * vv;
        }
      }
    }
  }
}

// ------------------------------- LayerNorm ---------------------------------
// warm: writes a_buf for all 12 layers AND copies x0 into states[0]
__global__ __launch_bounds__(256) void ln_warm_kernel(
    const float* __restrict__ x0, const float* __restrict__ g,
    const float* __restrict__ beta, bf16* __restrict__ a_buf,
    float* __restrict__ st0)
{
  const int row = blockIdx.x * 4 + (threadIdx.x >> 6);
  const int lane = threadIdx.x & 63;
  const float* x = x0 + (size_t)row * 768;
  float* s0 = st0 + (size_t)row * 768;
  float xl[12];
  float s1 = 0.f, s2 = 0.f;
  #pragma unroll
  for (int j = 0; j < 12; ++j) {
    float t = x[lane + 64 * j];
    xl[j] = t; s1 += t; s2 += t * t;
    s0[lane + 64 * j] = t;
  }
  #pragma unroll
  for (int off = 1; off < 64; off <<= 1) {
    s1 += __shfl_xor(s1, off);
    s2 += __shfl_xor(s2, off);
  }
  const float mu = s1 * (1.f / 768.f);
  const float var = s2 * (1.f / 768.f) - mu * mu;
  const float rstd = rsqrtf(var + 1e-5f);
  float xh[12];
  #pragma unroll
  for (int j = 0; j < 12; ++j) xh[j] = (xl[j] - mu) * rstd;
  for (int l = 0; l < 12; ++l) {
    const float* gp = g + l * 768;
    const float* bp = beta + l * 768;
    bf16* ap = a_buf + (size_t)l * LAY_A + (size_t)row * 768;
    #pragma unroll
    for (int j = 0; j < 12; ++j) {
      const int c = lane + 64 * j;
      ap[c] = (bf16)(xh[j] * gp[c] + bp[c]);
    }
  }
}

// iter: LN + LN-JVP with tangent v (v generated inline via threefry).
// Writes interleaved rows: token row -> a at 2*row, du at 2*row+1.
__global__ __launch_bounds__(256) void ln_iter_kernel(
    const float* __restrict__ states, bf16* __restrict__ vbuf,
    const float* __restrict__ g, const float* __restrict__ beta,
    bf16* __restrict__ a_buf, uint32_t k1, uint32_t k2)
{
  const int gr = blockIdx.x * 4 + (threadIdx.x >> 6);
  const int l = gr >> 10;
  const int row = gr & 1023;
  const int lane = threadIdx.x & 63;
  const float* x = states + (size_t)l * LAY_S + (size_t)row * 768;
  bf16* vp = vbuf + (size_t)gr * 768;
  float xl[12], vl[12];
  float s1 = 0.f, s2 = 0.f, sv = 0.f, sxv = 0.f;
  #pragma unroll
  for (int j = 0; j < 12; ++j) {
    const int c = lane + 64 * j;
    const float t = x[c];
    uint32_t o0, o1;
    threefry2x32(k1, k2, 0u, (uint32_t)gr * 768u + (uint32_t)c, o0, o1);
    const float u = ((o0 ^ o1) & 0x80000000u) ? 1.0f : -1.0f;
    vp[c] = (bf16)u;
    xl[j] = t; vl[j] = u;
    s1 += t; s2 += t * t; sv += u; sxv += t * u;
  }
  #pragma unroll
  for (int off = 1; off < 64; off <<= 1) {
    s1 += __shfl_xor(s1, off); s2 += __shfl_xor(s2, off);
    sv += __shfl_xor(sv, off); sxv += __shfl_xor(sxv, off);
  }
  const float mu = s1 * (1.f / 768.f);
  const float var = s2 * (1.f / 768.f) - mu * mu;
  const float rstd = rsqrtf(var + 1e-5f);
  const float mv = sv * (1.f / 768.f);
  const float mhv = rstd * (sxv * (1.f / 768.f) - mu * mv);
  const float* gp = g + l * 768;
  const float* bp = beta + l * 768;
  bf16* ap = a_buf + (size_t)l * LAY_A + (size_t)(2 * row) * 768;
  bf16* dp = ap + 768;
  #pragma unroll
  for (int j = 0; j < 12; ++j) {
    const int c = lane + 64 * j;
    const float xh = (xl[j] - mu) * rstd;
    ap[c] = (bf16)(xh * gp[c] + bp[c]);
    dp[c] = (bf16)(rstd * ((vl[j] - mv) - xh * mhv) * gp[c]);
  }
}

// --------------------- fused scan (it0) + ln_iter (it1) --------------------
// Per row (one wave each): walk l = 0..11; LN+JVP layer l from the
// register-held UPDATED states[l] (l=0: x0, untouched), then apply the scan
// step for layer l (run = res + A*run; states[l+1] += run) keeping the
// updated row in registers for the next layer's LN. Same arithmetic order
// as split scan_kernel + ln_iter_kernel.
__global__ __launch_bounds__(256) void scan_ln_kernel(
    const float* __restrict__ resA, float* __restrict__ states,
    const float* __restrict__ g, const float* __restrict__ beta,
    bf16* __restrict__ a_buf, bf16* __restrict__ vbuf,
    uint32_t k1, uint32_t k2)
{
  const int row = blockIdx.x * 4 + (threadIdx.x >> 6);   // 0..1023
  const int lane = threadIdx.x & 63;
  float cur[12], rn[12];
  #pragma unroll
  for (int j = 0; j < 12; ++j)
    cur[j] = states[(size_t)row * 768 + lane + 64 * j];  // states[0] = x0

  #pragma unroll 1
  for (int l = 0; l < 12; ++l) {
    // ---- LN + JVP of layer l (input: cur = updated states[l]) ----
    float vl[12];
    float s1 = 0.f, s2 = 0.f, sv = 0.f, sxv = 0.f;
    #pragma unroll
    for (int j = 0; j < 12; ++j) {
      const int c = lane + 64 * j;
      uint32_t o0, o1;
      threefry2x32(k1, k2, 0u,
                   (uint32_t)(l * 1024 + row) * 768u + (uint32_t)c, o0, o1);
      const float u = ((o0 ^ o1) & 0x80000000u) ? 1.0f : -1.0f;
      vbuf[(size_t)l * LAY_S + (size_t)row * 768 + c] = (bf16)u;
      vl[j] = u;
      const float t = cur[j];
      s1 += t; s2 += t * t; sv += u; sxv += t * u;
    }
    #pragma unroll
    for (int off = 1; off < 64; off <<= 1) {
      s1 += __shfl_xor(s1, off); s2 += __shfl_xor(s2, off);
      sv += __shfl_xor(sv, off); sxv += __shfl_xor(sxv, off);
    }
    const float mu = s1 * (1.f / 768.f);
    const float var = s2 * (1.f / 768.f) - mu * mu;
    const float rstd = rsqrtf(var + 1e-5f);
    const float mv = sv * (1.f / 768.f);
    const float mhv = rstd * (sxv * (1.f / 768.f) - mu * mv);
    const float* gp = g + l * 768;
    const float* bp = beta + l * 768;
    bf16* ap = a_buf + (size_t)l * LAY_A + (size_t)(2 * row) * 768;
    bf16* dp = ap + 768;
    #pragma unroll
    for (int j = 0; j < 12; ++j) {
      const int c = lane + 64 * j;
      const float xh = (cur[j] - mu) * rstd;
      ap[c] = (bf16)(xh * gp[c] + bp[c]);
      dp[c] = (bf16)(rstd * ((vl[j] - mv) - xh * mhv) * gp[c]);
    }
    // ---- scan step for layer l: run = res + A*run; cur = states[l+1]+run
    const float* Rp = resA + (size_t)l * LAY_A + (size_t)row * 768;
    float* Sp = states + (size_t)(l + 1) * LAY_S + (size_t)row * 768;
    #pragma unroll
    for (int j = 0; j < 12; ++j) {
      const int c = lane + 64 * j;
      const float b  = Rp[c];
      const float Aa = Rp[LAY_S + c];
      rn[j] = (l == 0) ? b : (b + Aa * rn[j]);
      const float v = Sp[c] + rn[j];
      Sp[c] = v;
      cur[j] = v;
    }
  }
}

// --------------------------- final scan (lite) -----------------------------
// states[1..11] are dead after the last iteration: compute the recurrence
// from resA only, read states[12], write d_out.
__global__ __launch_bounds__(256) void scan_final_kernel(
    const float* __restrict__ resA, const float* __restrict__ states,
    float* __restrict__ dout)
{
  const size_t i = (size_t)blockIdx.x * 256 + threadIdx.x;
  float run = resA[i];
  #pragma unroll
  for (int l = 1; l < 12; ++l) {
    const float b  = resA[(size_t)l * LAY_A + i];
    const float Aa = resA[(size_t)l * LAY_A + LAY_S + i];
    run = b + Aa * run;
  }
  dout[i] = states[12ULL * LAY_S + i] + run;
}

// ------------------------------- launcher ----------------------------------
extern "C" void kernel_launch(void* const* d_in, const int* in_sizes, int n_in,
                              void* d_out, int out_size, void* d_ws, size_t ws_size,
                              hipStream_t stream)
{
  const float* x0   = (const float*)d_in[0];
  const float* w1   = (const float*)d_in[1];
  const float* b1   = (const float*)d_in[2];
  const float* w2   = (const float*)d_in[3];
  const float* b2   = (const float*)d_in[4];
  const float* g    = (const float*)d_in[5];
  const float* beta = (const float*)d_in[6];

  char* ws = (char*)d_ws;
  size_t off = 0;
  auto alloc = [&](size_t bytes) -> void* {
    void* p = ws + off;
    off += (bytes + 255) & ~(size_t)255;
    return p;
  };
  bf16*  w1t    = (bf16*)alloc(2ULL * 12 * LAY_W);
  bf16*  w2t    = (bf16*)alloc(2ULL * 12 * LAY_W);
  float* states = (float*)alloc(4ULL * 13 * LAY_S);
  bf16*  a_buf  = (bf16*)alloc(2ULL * 12 * LAY_A);
  bf16*  zh     = (bf16*)alloc(2ULL * 12 * LAY_Z);
  float* resA   = (float*)alloc(4ULL * 12 * LAY_A);
  bf16*  vbuf   = (bf16*)alloc(2ULL * 12 * LAY_S);

  transpose_kernel<<<dim3(96, 24, 12), 256, 0, stream>>>(w1, w1t, 768, 3072);
  transpose_kernel<<<dim3(24, 96, 12), 256, 0, stream>>>(w2, w2t, 3072, 768);

  // warm start: states[0] = x0 (fused); states[l+1] = block_l(x0)
  ln_warm_kernel<<<256, 256, 0, stream>>>(x0, g, beta, a_buf, states);
  gemm_dbuf<0><<<2304, 256, 0, stream>>>(a_buf, w1t, zh, states, resA, vbuf,
                                         b1, b2, x0, 8);
  gemm_dbuf<2><<<576, 256, 0, stream>>>(zh, w2t, nullptr, states, resA, vbuf,
                                        b1, b2, x0, 8);

  uint32_t k1a, k2a, k1b, k2b;
  threefry2x32(0u, 42u, 0u, 0u, k1a, k2a);   // fold_in(key, it=0)
  threefry2x32(0u, 42u, 0u, 1u, k1b, k2b);   // fold_in(key, it=1)

  // ---- iteration 0 ----
  ln_iter_kernel<<<3072, 256, 0, stream>>>(states, vbuf, g, beta, a_buf,
                                           k1a, k2a);
  gemm_dbuf<1><<<4608, 256, 0, stream>>>(a_buf, w1t, zh, states, resA, vbuf,
                                         b1, b2, x0, 16);
  gemm_dbuf<3><<<1152, 256, 0, stream>>>(zh, w2t, nullptr, states, resA, vbuf,
                                         b1, b2, x0, 16);
  // fused: scan update (it0) + LN/JVP + v-gen for it1
  scan_ln_kernel<<<256, 256, 0, stream>>>(resA, states, g, beta, a_buf, vbuf,
                                          k1b, k2b);

  // ---- iteration 1 ----
  gemm_dbuf<1><<<4608, 256, 0, stream>>>(a_buf, w1t, zh, states, resA, vbuf,
                                         b1, b2, x0, 16);
  gemm_dbuf<3><<<1152, 256, 0, stream>>>(zh, w2t, nullptr, states, resA, vbuf,
                                         b1, b2, x0, 16);
  scan_final_kernel<<<3072, 256, 0, stream>>>(resA, states, (float*)d_out);
}

// Round 16
// 974.149 us; speedup vs baseline: 1.0775x; 1.0775x over previous
//
#include <hip/hip_runtime.h>
#include <hip/hip_bf16.h>
#include <stdint.h>

// ---------------------------------------------------------------------------
// DEER forward, MI355X. L=12, B=2, T=512, C=768, F=3072, M=B*T=1024.
// bf16 MFMA GEMMs (fp32 accum), analytic JVP, threefry2x32 Rademacher v.
// R16: R14 (measured best, 993us) + REVERT of R15's scan_ln fusion (latency-
//      bound at 4 waves/CU, -57us) keeping only the independent win:
//      final scan "lite" (states[1..11] dead after it1 -> recurrence from
//      resA + states[12] read + d_out write; 153MB -> 81MB).
//      GEMM core/pipeline byte-identical to R14 (R7 structure).
// ---------------------------------------------------------------------------

typedef __bf16 bf16;
typedef __bf16 bf16x8 __attribute__((ext_vector_type(8)));
typedef float f32x4 __attribute__((ext_vector_type(4)));

#define LAY_A   1572864   // 2048*768
#define LAY_W   2359296   // 3072*768
#define LAY_Z   6291456   // 2048*3072
#define LAY_S   786432    // 1024*768

#define GLDS16(gp, lp) __builtin_amdgcn_global_load_lds(                      \
    (const __attribute__((address_space(1))) void*)(gp),                      \
    (__attribute__((address_space(3))) void*)(lp), 16, 0, 0)

#define WAITVM(N) asm volatile("s_waitcnt vmcnt(%0)" :: "n"(N) : "memory")
#define CFENCE()  asm volatile("" ::: "memory")

// ------------------------- threefry2x32 (host+device) ----------------------
#define TF_ROT(x0, x1, n) { x0 += x1; x1 = (x1 << n) | (x1 >> (32 - n)); x1 ^= x0; }
__host__ __device__ __forceinline__ void threefry2x32(
    uint32_t k1, uint32_t k2, uint32_t c0, uint32_t c1, uint32_t& o0, uint32_t& o1)
{
  const uint32_t ks2 = k1 ^ k2 ^ 0x1BD11BDAu;
  uint32_t x0 = c0 + k1, x1 = c1 + k2;
  TF_ROT(x0,x1,13) TF_ROT(x0,x1,15) TF_ROT(x0,x1,26) TF_ROT(x0,x1,6)
  x0 += k2;  x1 += ks2 + 1u;
  TF_ROT(x0,x1,17) TF_ROT(x0,x1,29) TF_ROT(x0,x1,16) TF_ROT(x0,x1,24)
  x0 += ks2; x1 += k1 + 2u;
  TF_ROT(x0,x1,13) TF_ROT(x0,x1,15) TF_ROT(x0,x1,26) TF_ROT(x0,x1,6)
  x0 += k1;  x1 += k2 + 3u;
  TF_ROT(x0,x1,17) TF_ROT(x0,x1,29) TF_ROT(x0,x1,16) TF_ROT(x0,x1,24)
  x0 += k2;  x1 += ks2 + 4u;
  TF_ROT(x0,x1,13) TF_ROT(x0,x1,15) TF_ROT(x0,x1,26) TF_ROT(x0,x1,6)
  x0 += ks2; x1 += k1 + 5u;
  o0 = x0; o1 = x1;
}

// --------------------- weight transpose fp32 -> bf16^T ---------------------
__global__ __launch_bounds__(256) void transpose_kernel(
    const float* __restrict__ w, bf16* __restrict__ wt, int R, int Cc)
{
  __shared__ float tile[32][33];
  const int l = blockIdx.z;
  const float* wp = w + (size_t)l * R * Cc;
  bf16* wtp = wt + (size_t)l * R * Cc;
  const int c0 = blockIdx.x * 32;
  const int r0 = blockIdx.y * 32;
  const int tx = threadIdx.x & 31, ty = threadIdx.x >> 5;
  #pragma unroll
  for (int q = 0; q < 4; ++q)
    tile[ty + q * 8][tx] = wp[(size_t)(r0 + ty + q * 8) * Cc + c0 + tx];
  __syncthreads();
  // packed bf16x2 stores: thread -> 2 output rows x 2 consecutive cols
  const int orow = threadIdx.x >> 4;        // 0..15
  const int oc   = (threadIdx.x & 15) * 2;  // even col
  #pragma unroll
  for (int q = 0; q < 2; ++q) {
    const int r = orow + q * 16;
    const unsigned short lo = __builtin_bit_cast(unsigned short,
                                                 (bf16)tile[oc][r]);
    const unsigned short hi = __builtin_bit_cast(unsigned short,
                                                 (bf16)tile[oc + 1][r]);
    *(unsigned int*)&wtp[(size_t)(c0 + r) * R + r0 + oc] =
        (unsigned int)lo | ((unsigned int)hi << 16);
  }
}

// ------------------------------ gelu helper --------------------------------
// tanh via native exp: t = 1 - 2/(e^{2u}+1). Limits correct at +/-inf.
__device__ __forceinline__ void gelu2(float z, float& h, float& dg)
{
  const float z2 = z * z;
  const float u = 0.7978845608028654f * (z + 0.044715f * z2 * z);
  const float e = __expf(2.0f * u);
  const float t = 1.0f - 2.0f / (e + 1.0f);
  h = 0.5f * z * (1.f + t);
  dg = 0.5f * (1.f + t) +
       0.5f * z * (1.f - t * t) * 0.7978845608028654f * (1.f + 0.134145f * z2);
}

// ------------------------------ GEMM core ----------------------------------
// True R7 kernel. 128x128 tile, BK=64, 256 threads = 4 waves (2M x 2N),
// per-wave 64x64 out. Depth-1 counted-vmcnt pipeline over 2 LDS buffers
// (64 KiB -> 2 blocks/CU for cross-block phase overlap).
// MODE 0: gemm1 warm  (M=1024): zh = gelu(acc + b1), all rows.
// MODE 1: gemm1 iter  (M=2048 interleaved): even h=gelu(z), odd dh=dg*dz.
// MODE 2: gemm2 warm : states[l+1] = acc + b2 + x0.
// MODE 3: gemm2 iter  (interleaved): even res, odd A = 1 + acc*v.
template <int MODE>
__global__ __launch_bounds__(256, 2) void gemm_dbuf(
    const bf16* __restrict__ Abase, const bf16* __restrict__ Bbase,
    bf16* __restrict__ zh_out, float* __restrict__ states,
    float* __restrict__ resA, const bf16* __restrict__ vbuf,
    const float* __restrict__ bias1, const float* __restrict__ b2,
    const float* __restrict__ x0, int Mt)
{
  constexpr int LDAB  = (MODE <= 1) ? 768 : 3072;
  constexpr int NKT   = (MODE <= 1) ? 12 : 48;      // K/64
  constexpr int NTN   = (MODE <= 1) ? 24 : 6;       // N/128
  constexpr int ACH   = 16;                 // A chunks (128 rows / 8)
  constexpr int BCH   = 16;                 // B chunks (128 rows / 8)
  constexpr int NCH   = (ACH + BCH) / 4;    // 8 loads per thread per tile
  constexpr int ABYTES = 16384;
  constexpr int TILE  = ABYTES + BCH * 1024;   // 32 KiB
  constexpr size_t LSA = (MODE <= 1) ? LAY_A : LAY_Z;

  __shared__ __align__(16) char lds[2][TILE];  // 64 KiB double buffer

  const int tid  = threadIdx.x;
  const int lane = tid & 63;
  const int wid  = tid >> 6;           // 0..3
  const int wr   = wid >> 1;           // 0..1  (M half)
  const int wc   = wid & 1;            // 0..1  (N half)
  const int r16  = lane & 15;
  const int hi   = lane >> 4;          // 0..3

  // T1: XCD-aware bijective swizzle (grids are multiples of 8)
  const int nwg = gridDim.x;
  const int bid = blockIdx.x;
  const int swz = (bid & 7) * (nwg >> 3) + (bid >> 3);
  const int per_l = Mt * NTN;
  const int l   = swz / per_l;
  const int rr_ = swz - l * per_l;
  const int mt  = rr_ / NTN;
  const int nt  = rr_ - mt * NTN;
  const int m0  = mt * 128, n0 = nt * 128;

  const bf16* A = Abase + (size_t)l * LSA   + (size_t)m0 * LDAB;
  const bf16* B = Bbase + (size_t)l * LAY_W + (size_t)n0 * LDAB;

  const int rsub = lane >> 3;               // 0..7 row within chunk
  const int c8   = (lane & 7) ^ rsub;       // swizzled 16B slot (involution)
  auto STAGE = [&](char* dst, int kt) {
    #pragma unroll
    for (int j = 0; j < NCH; ++j) {
      const int chunk = j * 4 + wid;
      if (chunk < ACH) {
        const int row = chunk * 8 + rsub;
        GLDS16(A + (size_t)row * LDAB + kt + c8 * 8, dst + chunk * 1024);
      } else {
        const int row = (chunk - ACH) * 8 + rsub;
        GLDS16(B + (size_t)row * LDAB + kt + c8 * 8,
               dst + ABYTES + (chunk - ACH) * 1024);
      }
    }
  };

  f32x4 acc[4][4] = {};

  auto COMPUTE = [&](const char* buf) {
    const char* As = buf;
    const char* Bs = buf + ABYTES;
    const int xw = (r16 & 7) << 4;        // read-side XOR (matches staging)
    #pragma unroll
    for (int kk = 0; kk < 2; ++kk) {
      const int cb = kk * 64;
      bf16x8 bfrag[4];
      #pragma unroll
      for (int ni = 0; ni < 4; ++ni) {
        const int rn = wc * 64 + ni * 16 + r16;
        bfrag[ni] = *(const bf16x8*)(Bs + rn * 128 + ((cb + hi * 16) ^ xw));
      }
      bf16x8 afrag[4];
      #pragma unroll
      for (int q = 0; q < 4; ++q) {
        const int rm = wr * 64 + q * 16 + r16;
        afrag[q] = *(const bf16x8*)(As + rm * 128 + ((cb + hi * 16) ^ xw));
      }
      #pragma unroll
      for (int q = 0; q < 4; ++q)
        #pragma unroll
        for (int ni = 0; ni < 4; ++ni)
          acc[q][ni] = __builtin_amdgcn_mfma_f32_16x16x32_bf16(
              afrag[q], bfrag[ni], acc[q][ni], 0, 0, 0);
    }
  };

  // ---- depth-1 counted-vmcnt pipeline (R5-proven) ----
  STAGE(lds[0], 0);
  STAGE(lds[1], 64);
  WAITVM(NCH);                         // tile 0 landed; tile 1 in flight
  __builtin_amdgcn_s_barrier();
  CFENCE();
  COMPUTE(lds[0]);
  #pragma unroll 1
  for (int t = 1; t < NKT; ++t) {
    CFENCE();
    __builtin_amdgcn_s_barrier();      // all waves done reading buf[(t+1)&1]
    CFENCE();
    if (t + 1 < NKT) {
      STAGE(lds[(t + 1) & 1], (t + 1) * 64);
      WAITVM(NCH);                     // tile t landed; t+1 stays in flight
    } else {
      WAITVM(0);                       // last tile: drain
    }
    __builtin_amdgcn_s_barrier();      // cross-wave: tile t visible to all
    CFENCE();
    COMPUTE(lds[t & 1]);
  }

  // ------------------------------ epilogue ---------------------------------
  #pragma unroll
  for (int mi = 0; mi < 4; ++mi) {
    const int row0 = m0 + wr * 64 + mi * 16 + hi * 4;
    #pragma unroll
    for (int ni = 0; ni < 4; ++ni) {
      const int col = n0 + wc * 64 + ni * 16 + r16;
      if (MODE == 0) {                  // warm gemm1: h = gelu(z), all rows
        bf16* Cp = zh_out + (size_t)l * LAY_Z;
        const float bias = bias1[l * 3072 + col];
        #pragma unroll
        for (int r = 0; r < 4; ++r) {
          float h, dg;
          gelu2(acc[mi][ni][r] + bias, h, dg);
          Cp[(size_t)(row0 + r) * 3072 + col] = (bf16)h;
        }
      } else if (MODE == 1) {           // iter gemm1: row pairs (z, dz)
        bf16* Cp = zh_out + (size_t)l * LAY_Z;
        const float bias = bias1[l * 3072 + col];
        #pragma unroll
        for (int p = 0; p < 2; ++p) {
          float h, dg;
          gelu2(acc[mi][ni][2 * p] + bias, h, dg);
          Cp[(size_t)(row0 + 2 * p) * 3072 + col] = (bf16)h;
          Cp[(size_t)(row0 + 2 * p + 1) * 3072 + col] =
              (bf16)(dg * acc[mi][ni][2 * p + 1]);
        }
      } else if (MODE == 2) {           // warm gemm2
        float* Sp = states + (size_t)(l + 1) * LAY_S;
        const float bb = b2[l * 768 + col];
        #pragma unroll
        for (int r = 0; r < 4; ++r)
          Sp[(size_t)(row0 + r) * 768 + col] =
              acc[mi][ni][r] + bb + x0[(size_t)(row0 + r) * 768 + col];
      } else {                          // iter gemm2: row pairs (res, Adiag)
        float* Rp = resA + (size_t)l * LAY_A;
        const float bb = b2[l * 768 + col];
        #pragma unroll
        for (int p = 0; p < 2; ++p) {
          const int tok = (row0 >> 1) + p;          // rows row0+2p, +2p+1
          Rp[(size_t)tok * 768 + col] = acc[mi][ni][2 * p] + bb
              + states[(size_t)l * LAY_S + (size_t)tok * 768 + col]
              - states[(size_t)(l + 1) * LAY_S + (size_t)tok * 768 + col];
          const float vv = (float)vbuf[(size_t)l * LAY_S +
                                       (size_t)tok * 768 + col];
          Rp[LAY_S + (size_t)tok * 768 + col] =
              1.0f + acc[mi][ni][2 * p + 1] * vv;
        }
      }
    }
  }
}

// ------------------------------- LayerNorm ---------------------------------
// warm: writes a_buf for all 12 layers AND copies x0 into states[0]
__global__ __launch_bounds__(256) void ln_warm_kernel(
    const float* __restrict__ x0, const float* __restrict__ g,
    const float* __restrict__ beta, bf16* __restrict__ a_buf,
    float* __restrict__ st0)
{
  const int row = blockIdx.x * 4 + (threadIdx.x >> 6);
  const int lane = threadIdx.x & 63;
  const float* x = x0 + (size_t)row * 768;
  float* s0 = st0 + (size_t)row * 768;
  float xl[12];
  float s1 = 0.f, s2 = 0.f;
  #pragma unroll
  for (int j = 0; j < 12; ++j) {
    float t = x[lane + 64 * j];
    xl[j] = t; s1 += t; s2 += t * t;
    s0[lane + 64 * j] = t;
  }
  #pragma unroll
  for (int off = 1; off < 64; off <<= 1) {
    s1 += __shfl_xor(s1, off);
    s2 += __shfl_xor(s2, off);
  }
  const float mu = s1 * (1.f / 768.f);
  const float var = s2 * (1.f / 768.f) - mu * mu;
  const float rstd = rsqrtf(var + 1e-5f);
  float xh[12];
  #pragma unroll
  for (int j = 0; j < 12; ++j) xh[j] = (xl[j] - mu) * rstd;
  for (int l = 0; l < 12; ++l) {
    const float* gp = g + l * 768;
    const float* bp = beta + l * 768;
    bf16* ap = a_buf + (size_t)l * LAY_A + (size_t)row * 768;
    #pragma unroll
    for (int j = 0; j < 12; ++j) {
      const int c = lane + 64 * j;
      ap[c] = (bf16)(xh[j] * gp[c] + bp[c]);
    }
  }
}

// iter: LN + LN-JVP with tangent v (v generated inline via threefry).
// Writes interleaved rows: token row -> a at 2*row, du at 2*row+1.
__global__ __launch_bounds__(256) void ln_iter_kernel(
    const float* __restrict__ states, bf16* __restrict__ vbuf,
    const float* __restrict__ g, const float* __restrict__ beta,
    bf16* __restrict__ a_buf, uint32_t k1, uint32_t k2)
{
  const int gr = blockIdx.x * 4 + (threadIdx.x >> 6);
  const int l = gr >> 10;
  const int row = gr & 1023;
  const int lane = threadIdx.x & 63;
  const float* x = states + (size_t)l * LAY_S + (size_t)row * 768;
  bf16* vp = vbuf + (size_t)gr * 768;
  float xl[12], vl[12];
  float s1 = 0.f, s2 = 0.f, sv = 0.f, sxv = 0.f;
  #pragma unroll
  for (int j = 0; j < 12; ++j) {
    const int c = lane + 64 * j;
    const float t = x[c];
    uint32_t o0, o1;
    threefry2x32(k1, k2, 0u, (uint32_t)gr * 768u + (uint32_t)c, o0, o1);
    const float u = ((o0 ^ o1) & 0x80000000u) ? 1.0f : -1.0f;
    vp[c] = (bf16)u;
    xl[j] = t; vl[j] = u;
    s1 += t; s2 += t * t; sv += u; sxv += t * u;
  }
  #pragma unroll
  for (int off = 1; off < 64; off <<= 1) {
    s1 += __shfl_xor(s1, off); s2 += __shfl_xor(s2, off);
    sv += __shfl_xor(sv, off); sxv += __shfl_xor(sxv, off);
  }
  const float mu = s1 * (1.f / 768.f);
  const float var = s2 * (1.f / 768.f) - mu * mu;
  const float rstd = rsqrtf(var + 1e-5f);
  const float mv = sv * (1.f / 768.f);
  const float mhv = rstd * (sxv * (1.f / 768.f) - mu * mv);
  const float* gp = g + l * 768;
  const float* bp = beta + l * 768;
  bf16* ap = a_buf + (size_t)l * LAY_A + (size_t)(2 * row) * 768;
  bf16* dp = ap + 768;
  #pragma unroll
  for (int j = 0; j < 12; ++j) {
    const int c = lane + 64 * j;
    const float xh = (xl[j] - mu) * rstd;
    ap[c] = (bf16)(xh * gp[c] + bp[c]);
    dp[c] = (bf16)(rstd * ((vl[j] - mv) - xh * mhv) * gp[c]);
  }
}

// --------------------------- scan + state update ---------------------------
// it0: full update (states[l+1] += delta_l) feeding it1's ln_iter.
__global__ __launch_bounds__(256) void scan_kernel(
    const float* __restrict__ resA, float* __restrict__ states)
{
  const size_t i = (size_t)blockIdx.x * 256 + threadIdx.x;
  float run = resA[i];
  states[LAY_S + i] += run;
  #pragma unroll
  for (int l = 1; l < 12; ++l) {
    const float b  = resA[(size_t)l * LAY_A + i];
    const float Aa = resA[(size_t)l * LAY_A + LAY_S + i];
    run = b + Aa * run;
    states[(size_t)(l + 1) * LAY_S + i] += run;
  }
}

// --------------------------- final scan (lite) -----------------------------
// states[1..11] dead after it1: recurrence from resA only + states[12] read
// + d_out write.
__global__ __launch_bounds__(256) void scan_final_kernel(
    const float* __restrict__ resA, const float* __restrict__ states,
    float* __restrict__ dout)
{
  const size_t i = (size_t)blockIdx.x * 256 + threadIdx.x;
  float run = resA[i];
  #pragma unroll
  for (int l = 1; l < 12; ++l) {
    const float b  = resA[(size_t)l * LAY_A + i];
    const float Aa = resA[(size_t)l * LAY_A + LAY_S + i];
    run = b + Aa * run;
  }
  dout[i] = states[12ULL * LAY_S + i] + run;
}

// ------------------------------- launcher ----------------------------------
extern "C" void kernel_launch(void* const* d_in, const int* in_sizes, int n_in,
                              void* d_out, int out_size, void* d_ws, size_t ws_size,
                              hipStream_t stream)
{
  const float* x0   = (const float*)d_in[0];
  const float* w1   = (const float*)d_in[1];
  const float* b1   = (const float*)d_in[2];
  const float* w2   = (const float*)d_in[3];
  const float* b2   = (const float*)d_in[4];
  const float* g    = (const float*)d_in[5];
  const float* beta = (const float*)d_in[6];

  char* ws = (char*)d_ws;
  size_t off = 0;
  auto alloc = [&](size_t bytes) -> void* {
    void* p = ws + off;
    off += (bytes + 255) & ~(size_t)255;
    return p;
  };
  bf16*  w1t    = (bf16*)alloc(2ULL * 12 * LAY_W);
  bf16*  w2t    = (bf16*)alloc(2ULL * 12 * LAY_W);
  float* states = (float*)alloc(4ULL * 13 * LAY_S);
  bf16*  a_buf  = (bf16*)alloc(2ULL * 12 * LAY_A);
  bf16*  zh     = (bf16*)alloc(2ULL * 12 * LAY_Z);
  float* resA   = (float*)alloc(4ULL * 12 * LAY_A);
  bf16*  vbuf   = (bf16*)alloc(2ULL * 12 * LAY_S);

  transpose_kernel<<<dim3(96, 24, 12), 256, 0, stream>>>(w1, w1t, 768, 3072);
  transpose_kernel<<<dim3(24, 96, 12), 256, 0, stream>>>(w2, w2t, 3072, 768);

  // warm start: states[0] = x0 (fused); states[l+1] = block_l(x0)
  ln_warm_kernel<<<256, 256, 0, stream>>>(x0, g, beta, a_buf, states);
  gemm_dbuf<0><<<2304, 256, 0, stream>>>(a_buf, w1t, zh, states, resA, vbuf,
                                         b1, b2, x0, 8);
  gemm_dbuf<2><<<576, 256, 0, stream>>>(zh, w2t, nullptr, states, resA, vbuf,
                                        b1, b2, x0, 8);

  uint32_t k1a, k2a, k1b, k2b;
  threefry2x32(0u, 42u, 0u, 0u, k1a, k2a);   // fold_in(key, it=0)
  threefry2x32(0u, 42u, 0u, 1u, k1b, k2b);   // fold_in(key, it=1)

  // ---- iteration 0 ----
  ln_iter_kernel<<<3072, 256, 0, stream>>>(states, vbuf, g, beta, a_buf,
                                           k1a, k2a);
  gemm_dbuf<1><<<4608, 256, 0, stream>>>(a_buf, w1t, zh, states, resA, vbuf,
                                         b1, b2, x0, 16);
  gemm_dbuf<3><<<1152, 256, 0, stream>>>(zh, w2t, nullptr, states, resA, vbuf,
                                         b1, b2, x0, 16);
  scan_kernel<<<3072, 256, 0, stream>>>(resA, states);

  // ---- iteration 1 ----
  ln_iter_kernel<<<3072, 256, 0, stream>>>(states, vbuf, g, beta, a_buf,
                                           k1b, k2b);
  gemm_dbuf<1><<<4608, 256, 0, stream>>>(a_buf, w1t, zh, states, resA, vbuf,
                                         b1, b2, x0, 16);
  gemm_dbuf<3><<<1152, 256, 0, stream>>>(zh, w2t, nullptr, states, resA, vbuf,
                                         b1, b2, x0, 16);
  scan_final_kernel<<<3072, 256, 0, stream>>>(resA, states, (float*)d_out);
}